// Round 2
// baseline (331.003 us; speedup 1.0000x reference)
//
#include <hip/hip_runtime.h>

#define HW 4096
#define CC 128
#define NB 4
#define NSPLIT 4
#define KEYS_PER_SPLIT (HW / NSPLIT)

typedef __bf16 bf16x8 __attribute__((ext_vector_type(8)));
typedef float floatx4 __attribute__((ext_vector_type(4)));

// ---------------------------------------------------------------------------
// Weight conversion: wq|wk|wv fp32 -> contiguous bf16 [3][128][128]
// ---------------------------------------------------------------------------
__global__ __launch_bounds__(256) void wconv_kernel(
    const float* __restrict__ wq, const float* __restrict__ wk,
    const float* __restrict__ wv, __bf16* __restrict__ wb)
{
    int idx = blockIdx.x * 256 + threadIdx.x;      // grid 192 -> 49152 elems
    int which = idx >> 14;
    int within = idx & 16383;
    const float* src = (which == 0) ? wq : (which == 1) ? wk : wv;
    wb[idx] = (__bf16)src[within];
}

// ---------------------------------------------------------------------------
// Projection: one matrix (q/k/v) per block. Grid 768 = (n*64+it)*3+m.
// q,k -> [N][HW][C] bf16 (pixel-major); v -> [N][C][HW] bf16 (LDS transpose).
// ---------------------------------------------------------------------------
__global__ __launch_bounds__(256) void proj_kernel(
    const float* __restrict__ x, const __bf16* __restrict__ wb,
    const float* __restrict__ bq, const float* __restrict__ bk,
    const float* __restrict__ bv,
    __bf16* __restrict__ qb, __bf16* __restrict__ kb, __bf16* __restrict__ vb)
{
    __shared__ char smem_raw[128 * 70 * 2];        // 17.9 KB, unioned
    __bf16* Xt = reinterpret_cast<__bf16*>(smem_raw);   // [64][136]
    __bf16* Vt = reinterpret_cast<__bf16*>(smem_raw);   // [128][70]

    const int m   = blockIdx.x % 3;
    const int nit = blockIdx.x / 3;
    const int n   = nit >> 6;
    const int i0  = (nit & 63) << 6;
    const int t   = threadIdx.x;

    const float* xb = x + (size_t)n * CC * HW;

    // stage x^T tile [64 i][128 c] bf16, stride 136 (2-way banks = free)
#pragma unroll 4
    for (int p = 0; p < 32; ++p) {
        int c  = p * 4 + (t >> 6);
        int il = t & 63;
        Xt[il * 136 + c] = (__bf16)xb[(size_t)c * HW + i0 + il];
    }
    __syncthreads();

    const int w    = t >> 6;
    const int lane = t & 63;
    const int l16  = lane & 15;
    const int quad = lane >> 4;

    bf16x8 afrag[4];
#pragma unroll
    for (int ks = 0; ks < 4; ++ks)
        afrag[ks] = *reinterpret_cast<const bf16x8*>(
            &Xt[(w * 16 + l16) * 136 + ks * 32 + quad * 8]);

    const __bf16* wm = wb + (size_t)m * CC * CC;
    const float* Bm = (m == 0) ? bq : (m == 1) ? bk : bv;

    if (m < 2) {
        __bf16* dst = (m == 0) ? qb : kb;
#pragma unroll
        for (int h = 0; h < 8; ++h) {
            int d = h * 16 + l16;
            floatx4 acc = {0.f, 0.f, 0.f, 0.f};
#pragma unroll
            for (int ks = 0; ks < 4; ++ks) {
                bf16x8 bfrag = *reinterpret_cast<const bf16x8*>(
                    wm + (size_t)d * CC + ks * 32 + quad * 8);
                acc = __builtin_amdgcn_mfma_f32_16x16x32_bf16(afrag[ks], bfrag, acc, 0, 0, 0);
            }
            float bias = Bm[d];
#pragma unroll
            for (int r = 0; r < 4; ++r) {
                int i = i0 + w * 16 + quad * 4 + r;
                dst[(size_t)n * HW * CC + (size_t)i * CC + d] = (__bf16)(acc[r] + bias);
            }
        }
    } else {
        __syncthreads();   // all waves done reading Xt before Vt overwrites
#pragma unroll
        for (int h = 0; h < 8; ++h) {
            int d = h * 16 + l16;
            floatx4 acc = {0.f, 0.f, 0.f, 0.f};
#pragma unroll
            for (int ks = 0; ks < 4; ++ks) {
                bf16x8 bfrag = *reinterpret_cast<const bf16x8*>(
                    wm + (size_t)d * CC + ks * 32 + quad * 8);
                acc = __builtin_amdgcn_mfma_f32_16x16x32_bf16(afrag[ks], bfrag, acc, 0, 0, 0);
            }
            float bias = Bm[d];
#pragma unroll
            for (int r = 0; r < 4; ++r)
                Vt[d * 70 + w * 16 + quad * 4 + r] = (__bf16)(acc[r] + bias);
        }
        __syncthreads();
#pragma unroll 4
        for (int p = 0; p < 32; ++p) {
            int d  = p * 4 + (t >> 6);
            int il = t & 63;
            vb[((size_t)n * CC + d) * HW + i0 + il] = Vt[d * 70 + il];
        }
    }
}

// ---------------------------------------------------------------------------
// Flash attention, key-split: grid 1024 = (n*64+it)*4+split. Each block:
// 64 queries x 1024 keys, online softmax, writes UNNORMALIZED partial O
// [128 c][64 i] fp32 + per-row (m, l) to workspace.
// ---------------------------------------------------------------------------
__global__ __launch_bounds__(256) void attn_split_kernel(
    const __bf16* __restrict__ qb, const __bf16* __restrict__ kb,
    const __bf16* __restrict__ vb,
    float* __restrict__ opart, float* __restrict__ ml)
{
    __shared__ float smem[64 * 67];   // 17.2 KB: P tiles during loop, O^T after

    const int split = blockIdx.x & 3;
    const int it    = (blockIdx.x >> 2) & 63;
    const int n     = blockIdx.x >> 8;
    const int i0    = it << 6;
    const int t     = threadIdx.x;
    const int w     = t >> 6;
    const int lane  = t & 63;
    const int l16   = lane & 15;
    const int quad  = lane >> 4;

    // wave-private P tile: 16 rows x 72 bf16 (stride 144 B -> 2-way banks)
    __bf16* Pw = reinterpret_cast<__bf16*>(smem) + w * (16 * 72);

    const __bf16* qrow = qb + ((size_t)n * HW + i0 + w * 16 + l16) * CC;
    bf16x8 qfrag[4];
#pragma unroll
    for (int ks = 0; ks < 4; ++ks)
        qfrag[ks] = *reinterpret_cast<const bf16x8*>(qrow + ks * 32 + quad * 8);

    float m_i[4], l_i[4];
    floatx4 o_acc[8];
#pragma unroll
    for (int r = 0; r < 4; ++r) { m_i[r] = -1e30f; l_i[r] = 0.f; }
#pragma unroll
    for (int h = 0; h < 8; ++h) o_acc[h] = (floatx4){0.f, 0.f, 0.f, 0.f};

    const __bf16* kbase = kb + (size_t)n * HW * CC;
    const __bf16* vbase = vb + (size_t)n * CC * HW;

    const int jbeg = split * KEYS_PER_SPLIT;
    const int jend = jbeg + KEYS_PER_SPLIT;

    for (int j0 = jbeg; j0 < jend; j0 += 64) {
        // ---- S = Q^T K on a 16x64 subtile ----
        floatx4 s[4];
#pragma unroll
        for (int g = 0; g < 4; ++g) s[g] = (floatx4){0.f, 0.f, 0.f, 0.f};
#pragma unroll
        for (int ks = 0; ks < 4; ++ks) {
#pragma unroll
            for (int g = 0; g < 4; ++g) {
                bf16x8 kf = *reinterpret_cast<const bf16x8*>(
                    kbase + (size_t)(j0 + g * 16 + l16) * CC + ks * 32 + quad * 8);
                s[g] = __builtin_amdgcn_mfma_f32_16x16x32_bf16(qfrag[ks], kf, s[g], 0, 0, 0);
            }
        }

        // ---- online softmax (row state replicated across each quad) ----
        float rmax[4];
#pragma unroll
        for (int r = 0; r < 4; ++r)
            rmax[r] = fmaxf(fmaxf(s[0][r], s[1][r]), fmaxf(s[2][r], s[3][r]));
#pragma unroll
        for (int off = 1; off < 16; off <<= 1)
#pragma unroll
            for (int r = 0; r < 4; ++r)
                rmax[r] = fmaxf(rmax[r], __shfl_xor(rmax[r], off, 64));
        float alpha[4];
#pragma unroll
        for (int r = 0; r < 4; ++r) {
            float mn = fmaxf(m_i[r], rmax[r]);
            alpha[r] = __expf(m_i[r] - mn);
            m_i[r] = mn;
        }
#pragma unroll
        for (int g = 0; g < 4; ++g)
#pragma unroll
            for (int r = 0; r < 4; ++r)
                s[g][r] = __expf(s[g][r] - m_i[r]);
        float rsum[4];
#pragma unroll
        for (int r = 0; r < 4; ++r)
            rsum[r] = s[0][r] + s[1][r] + s[2][r] + s[3][r];
#pragma unroll
        for (int off = 1; off < 16; off <<= 1)
#pragma unroll
            for (int r = 0; r < 4; ++r)
                rsum[r] += __shfl_xor(rsum[r], off, 64);
#pragma unroll
        for (int r = 0; r < 4; ++r)
            l_i[r] = l_i[r] * alpha[r] + rsum[r];
#pragma unroll
        for (int h = 0; h < 8; ++h)
#pragma unroll
            for (int r = 0; r < 4; ++r)
                o_acc[h][r] *= alpha[r];

        // ---- P: C/D layout -> LDS -> A-operand layout (wave-private) ----
#pragma unroll
        for (int g = 0; g < 4; ++g)
#pragma unroll
            for (int r = 0; r < 4; ++r)
                Pw[(quad * 4 + r) * 72 + g * 16 + l16] = (__bf16)s[g][r];

        bf16x8 pfrag[2];
#pragma unroll
        for (int tt = 0; tt < 2; ++tt)
            pfrag[tt] = *reinterpret_cast<const bf16x8*>(Pw + l16 * 72 + tt * 32 + quad * 8);

        // ---- O += P V^T ----
#pragma unroll
        for (int tt = 0; tt < 2; ++tt)
#pragma unroll
            for (int h = 0; h < 8; ++h) {
                bf16x8 vf = *reinterpret_cast<const bf16x8*>(
                    vbase + (size_t)(h * 16 + l16) * HW + j0 + tt * 32 + quad * 8);
                o_acc[h] = __builtin_amdgcn_mfma_f32_16x16x32_bf16(pfrag[tt], vf, o_acc[h], 0, 0, 0);
            }
    }

    // ---- epilogue: unnormalized O -> LDS transpose -> opart; (m,l) -> ml ----
    __syncthreads();
#pragma unroll
    for (int h = 0; h < 8; ++h)
#pragma unroll
        for (int r = 0; r < 4; ++r)
            smem[(w * 16 + quad * 4 + r) * 67 + h * 16 + l16] = o_acc[h][r];
    __syncthreads();

    const size_t pbase = (size_t)blockIdx.x * CC * 64;
#pragma unroll 4
    for (int p = 0; p < 32; ++p) {
        int c  = p * 4 + (t >> 6);
        int il = t & 63;
        opart[pbase + (size_t)c * 64 + il] = smem[il * 67 + c];
    }
    if (l16 == 0) {
        const size_t mbase = (size_t)blockIdx.x * 128;
#pragma unroll
        for (int r = 0; r < 4; ++r) {
            int row = w * 16 + quad * 4 + r;
            ml[mbase + row]      = m_i[r];
            ml[mbase + 64 + row] = l_i[r];
        }
    }
}

// ---------------------------------------------------------------------------
// Combine: grid 256 = n*64+it. Merge 4 splits, normalize, out = gamma*O + x.
// ---------------------------------------------------------------------------
__global__ __launch_bounds__(256) void combine_kernel(
    const float* __restrict__ opart, const float* __restrict__ ml,
    const float* __restrict__ x, const float* __restrict__ gamma,
    float* __restrict__ out)
{
    __shared__ float wsc[NSPLIT][64];

    const int b  = blockIdx.x;
    const int n  = b >> 6;
    const int i0 = (b & 63) << 6;
    const int t  = threadIdx.x;
    const float gm = gamma[0];

    if (t < 64) {
        float ms[NSPLIT], ls[NSPLIT];
        float M = -1e30f;
#pragma unroll
        for (int s = 0; s < NSPLIT; ++s) {
            ms[s] = ml[(size_t)(b * 4 + s) * 128 + t];
            ls[s] = ml[(size_t)(b * 4 + s) * 128 + 64 + t];
            M = fmaxf(M, ms[s]);
        }
        float denom = 0.f;
        float es[NSPLIT];
#pragma unroll
        for (int s = 0; s < NSPLIT; ++s) {
            es[s] = __expf(ms[s] - M);
            denom += es[s] * ls[s];
        }
        float inv = gm / denom;
#pragma unroll
        for (int s = 0; s < NSPLIT; ++s)
            wsc[s][t] = es[s] * inv;
    }
    __syncthreads();

#pragma unroll 4
    for (int p = 0; p < 32; ++p) {
        int c  = p * 4 + (t >> 6);
        int il = t & 63;
        size_t gidx = ((size_t)n * CC + c) * HW + i0 + il;
        float acc = x[gidx];
#pragma unroll
        for (int s = 0; s < NSPLIT; ++s)
            acc += wsc[s][il] * opart[((size_t)(b * 4 + s) * CC + c) * 64 + il];
        out[gidx] = acc;
    }
}

extern "C" void kernel_launch(void* const* d_in, const int* in_sizes, int n_in,
                              void* d_out, int out_size, void* d_ws, size_t ws_size,
                              hipStream_t stream) {
    const float* x     = (const float*)d_in[0];
    const float* wq    = (const float*)d_in[1];
    const float* bq    = (const float*)d_in[2];
    const float* wk    = (const float*)d_in[3];
    const float* bk    = (const float*)d_in[4];
    const float* wv    = (const float*)d_in[5];
    const float* bv    = (const float*)d_in[6];
    const float* gamma = (const float*)d_in[7];
    float* out = (float*)d_out;

    char* ws = (char*)d_ws;
    const size_t qkv_sz = (size_t)NB * HW * CC * sizeof(__bf16);   // 4 MB each
    __bf16* qb = (__bf16*)(ws);
    __bf16* kb = (__bf16*)(ws + qkv_sz);
    __bf16* vb = (__bf16*)(ws + 2 * qkv_sz);
    __bf16* wb = (__bf16*)(ws + 3 * qkv_sz);                       // 96 KB
    float* opart = (float*)(ws + 3 * qkv_sz + 3 * CC * CC * sizeof(__bf16));
    float* ml    = (float*)((char*)opart +
                            (size_t)NB * 64 * NSPLIT * CC * 64 * sizeof(float)); // 32 MB

    wconv_kernel<<<192, 256, 0, stream>>>(wq, wk, wv, wb);
    proj_kernel<<<768, 256, 0, stream>>>(x, wb, bq, bk, bv, qb, kb, vb);
    attn_split_kernel<<<1024, 256, 0, stream>>>(qb, kb, vb, opart, ml);
    combine_kernel<<<256, 256, 0, stream>>>(opart, ml, x, gamma, out);
}

// Round 3
// 163.387 us; speedup vs baseline: 2.0259x; 2.0259x over previous
//
#include <hip/hip_runtime.h>

#define HW 4096
#define CC 128
#define NB 4
#define NSPLIT 4
#define KEYS_PER_SPLIT (HW / NSPLIT)

typedef __bf16 bf16x8 __attribute__((ext_vector_type(8)));
typedef float floatx4 __attribute__((ext_vector_type(4)));

// 16-lane (DPP row) butterfly reductions on the VALU pipe — no DS traffic.
__device__ __forceinline__ float row_max16(float v) {
    int x;
    x = __builtin_amdgcn_update_dpp(0, __float_as_int(v), 0x128, 0xf, 0xf, false);
    v = fmaxf(v, __int_as_float(x));
    x = __builtin_amdgcn_update_dpp(0, __float_as_int(v), 0x124, 0xf, 0xf, false);
    v = fmaxf(v, __int_as_float(x));
    x = __builtin_amdgcn_update_dpp(0, __float_as_int(v), 0x122, 0xf, 0xf, false);
    v = fmaxf(v, __int_as_float(x));
    x = __builtin_amdgcn_update_dpp(0, __float_as_int(v), 0x121, 0xf, 0xf, false);
    v = fmaxf(v, __int_as_float(x));
    return v;
}
__device__ __forceinline__ float row_sum16(float v) {
    int x;
    x = __builtin_amdgcn_update_dpp(0, __float_as_int(v), 0x128, 0xf, 0xf, false);
    v += __int_as_float(x);
    x = __builtin_amdgcn_update_dpp(0, __float_as_int(v), 0x124, 0xf, 0xf, false);
    v += __int_as_float(x);
    x = __builtin_amdgcn_update_dpp(0, __float_as_int(v), 0x122, 0xf, 0xf, false);
    v += __int_as_float(x);
    x = __builtin_amdgcn_update_dpp(0, __float_as_int(v), 0x121, 0xf, 0xf, false);
    v += __int_as_float(x);
    return v;
}

// ---------------------------------------------------------------------------
// Weight conversion: wq|wk|wv fp32 -> contiguous bf16 [3][128][128]
// ---------------------------------------------------------------------------
__global__ __launch_bounds__(256) void wconv_kernel(
    const float* __restrict__ wq, const float* __restrict__ wk,
    const float* __restrict__ wv, __bf16* __restrict__ wb)
{
    int idx = blockIdx.x * 256 + threadIdx.x;      // grid 192 -> 49152 elems
    int which = idx >> 14;
    int within = idx & 16383;
    const float* src = (which == 0) ? wq : (which == 1) ? wk : wv;
    wb[idx] = (__bf16)src[within];
}

// ---------------------------------------------------------------------------
// Projection: one matrix (q/k/v) per block. Grid 768 = (n*64+it)*3+m.
// q,k -> [N][HW][C] bf16 (pixel-major); v -> [N][C][HW] bf16 (LDS transpose).
// ---------------------------------------------------------------------------
__global__ __launch_bounds__(256) void proj_kernel(
    const float* __restrict__ x, const __bf16* __restrict__ wb,
    const float* __restrict__ bq, const float* __restrict__ bk,
    const float* __restrict__ bv,
    __bf16* __restrict__ qb, __bf16* __restrict__ kb, __bf16* __restrict__ vb)
{
    __shared__ char smem_raw[128 * 70 * 2];        // 17.9 KB, unioned
    __bf16* Xt = reinterpret_cast<__bf16*>(smem_raw);   // [64][136]
    __bf16* Vt = reinterpret_cast<__bf16*>(smem_raw);   // [128][70]

    const int m   = blockIdx.x % 3;
    const int nit = blockIdx.x / 3;
    const int n   = nit >> 6;
    const int i0  = (nit & 63) << 6;
    const int t   = threadIdx.x;

    const float* xb = x + (size_t)n * CC * HW;

#pragma unroll 4
    for (int p = 0; p < 32; ++p) {
        int c  = p * 4 + (t >> 6);
        int il = t & 63;
        Xt[il * 136 + c] = (__bf16)xb[(size_t)c * HW + i0 + il];
    }
    __syncthreads();

    const int w    = t >> 6;
    const int lane = t & 63;
    const int l16  = lane & 15;
    const int quad = lane >> 4;

    bf16x8 afrag[4];
#pragma unroll
    for (int ks = 0; ks < 4; ++ks)
        afrag[ks] = *reinterpret_cast<const bf16x8*>(
            &Xt[(w * 16 + l16) * 136 + ks * 32 + quad * 8]);

    const __bf16* wm = wb + (size_t)m * CC * CC;
    const float* Bm = (m == 0) ? bq : (m == 1) ? bk : bv;

    if (m < 2) {
        __bf16* dst = (m == 0) ? qb : kb;
#pragma unroll
        for (int h = 0; h < 8; ++h) {
            int d = h * 16 + l16;
            floatx4 acc = {0.f, 0.f, 0.f, 0.f};
#pragma unroll
            for (int ks = 0; ks < 4; ++ks) {
                bf16x8 bfrag = *reinterpret_cast<const bf16x8*>(
                    wm + (size_t)d * CC + ks * 32 + quad * 8);
                acc = __builtin_amdgcn_mfma_f32_16x16x32_bf16(afrag[ks], bfrag, acc, 0, 0, 0);
            }
            float bias = Bm[d];
#pragma unroll
            for (int r = 0; r < 4; ++r) {
                int i = i0 + w * 16 + quad * 4 + r;
                dst[(size_t)n * HW * CC + (size_t)i * CC + d] = (__bf16)(acc[r] + bias);
            }
        }
    } else {
        __syncthreads();
#pragma unroll
        for (int h = 0; h < 8; ++h) {
            int d = h * 16 + l16;
            floatx4 acc = {0.f, 0.f, 0.f, 0.f};
#pragma unroll
            for (int ks = 0; ks < 4; ++ks) {
                bf16x8 bfrag = *reinterpret_cast<const bf16x8*>(
                    wm + (size_t)d * CC + ks * 32 + quad * 8);
                acc = __builtin_amdgcn_mfma_f32_16x16x32_bf16(afrag[ks], bfrag, acc, 0, 0, 0);
            }
            float bias = Bm[d];
#pragma unroll
            for (int r = 0; r < 4; ++r)
                Vt[d * 70 + w * 16 + quad * 4 + r] = (__bf16)(acc[r] + bias);
        }
        __syncthreads();
#pragma unroll 4
        for (int p = 0; p < 32; ++p) {
            int d  = p * 4 + (t >> 6);
            int il = t & 63;
            vb[((size_t)n * CC + d) * HW + i0 + il] = Vt[d * 70 + il];
        }
    }
}

// ---------------------------------------------------------------------------
// Flash attention, key-split, LDS-staged K/V, 128 q/block (32 q/wave).
// Grid 512; block b -> XCD b&7 heuristic: n=(b>>1)&3 pins batch to XCD pair
// so each XCD's K/V working set (2 MB) fits its 4 MB L2.
// ---------------------------------------------------------------------------
#define KT_STRIDE 136   // bf16 elems; 272 B row (16B-aligned, uniform banks)
#define VT_STRIDE 72    // bf16 elems; 144 B row
#define PT_STRIDE 72
#define KT_BYTES (64 * KT_STRIDE * 2)          // 17408
#define VT_BYTES (128 * VT_STRIDE * 2)         // 18432
#define P_OFF    (KT_BYTES + VT_BYTES)         // 35840
#define T_STRIDE 129    // fp32 elems (epilogue transpose, aliases Kt/Vt)

__global__ __launch_bounds__(256, 2) void attn_split_kernel(
    const __bf16* __restrict__ qb, const __bf16* __restrict__ kb,
    const __bf16* __restrict__ vb,
    float* __restrict__ opart, float* __restrict__ ml)
{
    __shared__ char smem[P_OFF + 4 * 32 * PT_STRIDE * 2];   // 54272 B
    __bf16* Kt = reinterpret_cast<__bf16*>(smem);
    __bf16* Vt = reinterpret_cast<__bf16*>(smem + KT_BYTES);
    float*  T  = reinterpret_cast<float*>(smem);            // epilogue alias

    const int b     = blockIdx.x;
    const int n     = (b >> 1) & 3;
    const int split = (((b >> 3) & 1) << 1) | (b & 1);
    const int it    = b >> 4;                 // 0..31
    const int i0    = it << 7;                // *128
    const int t     = threadIdx.x;
    const int w     = t >> 6;
    const int lane  = t & 63;
    const int l16   = lane & 15;
    const int quad  = lane >> 4;

    __bf16* Pw = reinterpret_cast<__bf16*>(smem + P_OFF) + w * (32 * PT_STRIDE);

    // Q fragments for 32 queries (2 halves of 16) pinned in registers
    bf16x8 qfrag[2][4];
#pragma unroll
    for (int half = 0; half < 2; ++half) {
        const __bf16* qrow = qb + ((size_t)n * HW + i0 + w * 32 + half * 16 + l16) * CC;
#pragma unroll
        for (int ks = 0; ks < 4; ++ks)
            qfrag[half][ks] = *reinterpret_cast<const bf16x8*>(qrow + ks * 32 + quad * 8);
    }

    float m_i[2][4], l_i[2][4];
    floatx4 o_acc[2][8];
#pragma unroll
    for (int half = 0; half < 2; ++half) {
#pragma unroll
        for (int r = 0; r < 4; ++r) { m_i[half][r] = -1e30f; l_i[half][r] = 0.f; }
#pragma unroll
        for (int h = 0; h < 8; ++h) o_acc[half][h] = (floatx4){0.f, 0.f, 0.f, 0.f};
    }

    const __bf16* kbase = kb + (size_t)n * HW * CC;
    const __bf16* vbase = vb + (size_t)n * CC * HW;

    const int jbeg = split * KEYS_PER_SPLIT;
    const int jend = jbeg + KEYS_PER_SPLIT;

    for (int j0 = jbeg; j0 < jend; j0 += 64) {
        // ---- stage K (64j x 128c) and V (128c x 64j) tiles into LDS ----
        bf16x8 kst[4], vst[4];
        const int jr = t >> 4, ch = t & 15;        // K: 16 rows/pass
        const int cv = t >> 3, ch2 = t & 7;        // V: 32 rows/pass
#pragma unroll
        for (int p = 0; p < 4; ++p) {
            kst[p] = *reinterpret_cast<const bf16x8*>(
                kbase + (size_t)(j0 + p * 16 + jr) * CC + ch * 8);
            vst[p] = *reinterpret_cast<const bf16x8*>(
                vbase + (size_t)(p * 32 + cv) * HW + j0 + ch2 * 8);
        }
        __syncthreads();   // previous iteration's readers done
#pragma unroll
        for (int p = 0; p < 4; ++p) {
            *reinterpret_cast<bf16x8*>(&Kt[(p * 16 + jr) * KT_STRIDE + ch * 8]) = kst[p];
            *reinterpret_cast<bf16x8*>(&Vt[(p * 32 + cv) * VT_STRIDE + ch2 * 8]) = vst[p];
        }
        __syncthreads();

        // ---- S = Q^T K : 2 halves x 4 j-subtiles, K frags read once ----
        floatx4 s[2][4];
#pragma unroll
        for (int half = 0; half < 2; ++half)
#pragma unroll
            for (int g = 0; g < 4; ++g) s[half][g] = (floatx4){0.f, 0.f, 0.f, 0.f};
#pragma unroll
        for (int ks = 0; ks < 4; ++ks) {
#pragma unroll
            for (int g = 0; g < 4; ++g) {
                bf16x8 kf = *reinterpret_cast<const bf16x8*>(
                    &Kt[(g * 16 + l16) * KT_STRIDE + ks * 32 + quad * 8]);
                s[0][g] = __builtin_amdgcn_mfma_f32_16x16x32_bf16(qfrag[0][ks], kf, s[0][g], 0, 0, 0);
                s[1][g] = __builtin_amdgcn_mfma_f32_16x16x32_bf16(qfrag[1][ks], kf, s[1][g], 0, 0, 0);
            }
        }

        // ---- online softmax per half (DPP reductions, VALU-only) ----
#pragma unroll
        for (int half = 0; half < 2; ++half) {
            float alpha[4];
#pragma unroll
            for (int r = 0; r < 4; ++r) {
                float rm = fmaxf(fmaxf(s[half][0][r], s[half][1][r]),
                                 fmaxf(s[half][2][r], s[half][3][r]));
                rm = row_max16(rm);
                float mn = fmaxf(m_i[half][r], rm);
                alpha[r] = __expf(m_i[half][r] - mn);
                m_i[half][r] = mn;
            }
#pragma unroll
            for (int g = 0; g < 4; ++g)
#pragma unroll
                for (int r = 0; r < 4; ++r)
                    s[half][g][r] = __expf(s[half][g][r] - m_i[half][r]);
#pragma unroll
            for (int r = 0; r < 4; ++r) {
                float rs = s[half][0][r] + s[half][1][r] + s[half][2][r] + s[half][3][r];
                rs = row_sum16(rs);
                l_i[half][r] = l_i[half][r] * alpha[r] + rs;
            }
#pragma unroll
            for (int h = 0; h < 8; ++h)
#pragma unroll
                for (int r = 0; r < 4; ++r)
                    o_acc[half][h][r] *= alpha[r];
            // P: C/D layout -> LDS (wave-private)
#pragma unroll
            for (int g = 0; g < 4; ++g)
#pragma unroll
                for (int r = 0; r < 4; ++r)
                    Pw[(half * 16 + quad * 4 + r) * PT_STRIDE + g * 16 + l16] =
                        (__bf16)s[half][g][r];
        }

        // ---- O += P V^T : V frags read once, used by both halves ----
        bf16x8 pfrag[2][2];
#pragma unroll
        for (int half = 0; half < 2; ++half)
#pragma unroll
            for (int tt = 0; tt < 2; ++tt)
                pfrag[half][tt] = *reinterpret_cast<const bf16x8*>(
                    Pw + (half * 16 + l16) * PT_STRIDE + tt * 32 + quad * 8);
#pragma unroll
        for (int tt = 0; tt < 2; ++tt) {
#pragma unroll
            for (int h = 0; h < 8; ++h) {
                bf16x8 vf = *reinterpret_cast<const bf16x8*>(
                    &Vt[(h * 16 + l16) * VT_STRIDE + tt * 32 + quad * 8]);
                o_acc[0][h] = __builtin_amdgcn_mfma_f32_16x16x32_bf16(pfrag[0][tt], vf, o_acc[0][h], 0, 0, 0);
                o_acc[1][h] = __builtin_amdgcn_mfma_f32_16x16x32_bf16(pfrag[1][tt], vf, o_acc[1][h], 0, 0, 0);
            }
        }
    }

    // ---- (m, l) out ----
    if (l16 == 0) {
#pragma unroll
        for (int half = 0; half < 2; ++half)
#pragma unroll
            for (int r = 0; r < 4; ++r) {
                int row = w * 32 + half * 16 + quad * 4 + r;
                ml[(size_t)b * 256 + row]       = m_i[half][r];
                ml[(size_t)b * 256 + 128 + row] = l_i[half][r];
            }
    }

    // ---- epilogue: two 64-q passes through fp32 LDS transpose ----
    __syncthreads();   // Kt/Vt dead, safe to alias as T
#pragma unroll
    for (int pass = 0; pass < 2; ++pass) {
        if ((w >> 1) == pass) {
            int rb = (w & 1) * 32;
#pragma unroll
            for (int half = 0; half < 2; ++half)
#pragma unroll
                for (int h = 0; h < 8; ++h)
#pragma unroll
                    for (int r = 0; r < 4; ++r)
                        T[(rb + half * 16 + quad * 4 + r) * T_STRIDE + h * 16 + l16] =
                            o_acc[half][h][r];
        }
        __syncthreads();
#pragma unroll 4
        for (int p = 0; p < 32; ++p) {
            int c  = p * 4 + (t >> 6);
            int ql = t & 63;
            opart[(size_t)b * 16384 + (size_t)c * 128 + pass * 64 + ql] =
                T[ql * T_STRIDE + c];
        }
        __syncthreads();
    }
}

// ---------------------------------------------------------------------------
// Combine: grid 1024 = qt(128) x cpart(8). Merge 4 splits, out = gamma*O + x.
// ---------------------------------------------------------------------------
__global__ __launch_bounds__(256) void combine_kernel(
    const float* __restrict__ opart, const float* __restrict__ ml,
    const float* __restrict__ x, const float* __restrict__ gamma,
    float* __restrict__ out)
{
    __shared__ float wsc[NSPLIT][128];

    const int b2    = blockIdx.x;
    const int cpart = b2 & 7;
    const int qt    = b2 >> 3;       // 0..127
    const int n     = qt >> 5;
    const int it    = qt & 31;
    const int i0    = it << 7;
    const int t     = threadIdx.x;
    const float gm  = gamma[0];

    int battn[NSPLIT];
#pragma unroll
    for (int s = 0; s < NSPLIT; ++s)
        battn[s] = (it << 4) | ((s >> 1) << 3) | (n << 1) | (s & 1);

    if (t < 128) {
        float ms[NSPLIT], ls[NSPLIT], M = -1e30f;
#pragma unroll
        for (int s = 0; s < NSPLIT; ++s) {
            ms[s] = ml[(size_t)battn[s] * 256 + t];
            ls[s] = ml[(size_t)battn[s] * 256 + 128 + t];
            M = fmaxf(M, ms[s]);
        }
        float denom = 0.f, es[NSPLIT];
#pragma unroll
        for (int s = 0; s < NSPLIT; ++s) {
            es[s] = __expf(ms[s] - M);
            denom += es[s] * ls[s];
        }
        float inv = gm / denom;
#pragma unroll
        for (int s = 0; s < NSPLIT; ++s)
            wsc[s][t] = es[s] * inv;
    }
    __syncthreads();

#pragma unroll
    for (int p = 0; p < 8; ++p) {
        int cl = p * 2 + (t >> 7);
        int q  = t & 127;
        int c  = cpart * 16 + cl;
        size_t gidx = ((size_t)n * CC + c) * HW + i0 + q;
        float acc = x[gidx];
#pragma unroll
        for (int s = 0; s < NSPLIT; ++s)
            acc += wsc[s][q] * opart[(size_t)battn[s] * 16384 + (size_t)c * 128 + q];
        out[gidx] = acc;
    }
}

extern "C" void kernel_launch(void* const* d_in, const int* in_sizes, int n_in,
                              void* d_out, int out_size, void* d_ws, size_t ws_size,
                              hipStream_t stream) {
    const float* x     = (const float*)d_in[0];
    const float* wq    = (const float*)d_in[1];
    const float* bq    = (const float*)d_in[2];
    const float* wk    = (const float*)d_in[3];
    const float* bk    = (const float*)d_in[4];
    const float* wv    = (const float*)d_in[5];
    const float* bv    = (const float*)d_in[6];
    const float* gamma = (const float*)d_in[7];
    float* out = (float*)d_out;

    char* ws = (char*)d_ws;
    const size_t qkv_sz = (size_t)NB * HW * CC * sizeof(__bf16);   // 4 MB each
    __bf16* qb = (__bf16*)(ws);
    __bf16* kb = (__bf16*)(ws + qkv_sz);
    __bf16* vb = (__bf16*)(ws + 2 * qkv_sz);
    __bf16* wb = (__bf16*)(ws + 3 * qkv_sz);                       // 96 KB
    float* opart = (float*)(ws + 3 * qkv_sz + 3 * CC * CC * sizeof(__bf16));
    float* ml    = (float*)((char*)opart + (size_t)512 * CC * 128 * sizeof(float)); // 32 MB

    wconv_kernel<<<192, 256, 0, stream>>>(wq, wk, wv, wb);
    proj_kernel<<<768, 256, 0, stream>>>(x, wb, bq, bk, bv, qb, kb, vb);
    attn_split_kernel<<<512, 256, 0, stream>>>(qb, kb, vb, opart, ml);
    combine_kernel<<<1024, 256, 0, stream>>>(opart, ml, x, gamma, out);
}